// Round 12
// baseline (78.585 us; speedup 1.0000x reference)
//
#include <hip/hip_runtime.h>
#include <cfloat>

#define NFEAT 256
#define BATCH 4096
#define MTOT  16384
#define NSTRIP 32
#define STRIPW 512
#define NCH 32                // 16-col chunks per strip
#define UMARGIN 0.75f

typedef __attribute__((ext_vector_type(8))) short bf16x8;
typedef __attribute__((ext_vector_type(4))) float f32x4;

__device__ __forceinline__ unsigned bf16pack(float a, float b) {
    unsigned ua = __float_as_uint(a), ub = __float_as_uint(b);
    unsigned ra = (ua + 0x7fffu + ((ua >> 16) & 1u)) >> 16;
    unsigned rb = (ub + 0x7fffu + ((ub >> 16) & 1u)) >> 16;
    return ra | (rb << 16);
}

// ---------------------------------------------------------------------------
// Prep A: xb -> bf16 row-major + a2. One wave per row.
// ---------------------------------------------------------------------------
__global__ __launch_bounds__(256) void prep_a_kernel(const float* __restrict__ xb,
                                                     uint2* __restrict__ Abf,
                                                     float* __restrict__ a2) {
    int gid  = blockIdx.x * blockDim.x + threadIdx.x;
    int row  = gid >> 6;
    int lane = gid & 63;
    float4 v = ((const float4*)(xb + (size_t)row * NFEAT))[lane];
    Abf[(size_t)row * 64 + lane] = make_uint2(bf16pack(v.x, v.y), bf16pack(v.z, v.w));
    float s = v.x * v.x + v.y * v.y + v.z * v.z + v.w * v.w;
    #pragma unroll
    for (int off = 32; off > 0; off >>= 1) s += __shfl_down(s, off);
    if (lane == 0) a2[row] = s;
}

// ---------------------------------------------------------------------------
// Prep B: w -> bf16 in MFMA-FRAGMENT order + b2 (unchanged from round 11;
// layout verified absmax=0). Group g (16 cols), sub-block kk: 1024-B block
// where byte l*16 holds col g*16+(l&15), bf16 elems kk*32+(l>>4)*8 .. +8.
// ---------------------------------------------------------------------------
__global__ __launch_bounds__(256) void prep_b_kernel(const float* __restrict__ w,
                                                     uint4* __restrict__ Bfr,
                                                     float* __restrict__ b2) {
    const int t = threadIdx.x, l = t & 63;
    const int g = blockIdx.x * 4 + (t >> 6);        // 0..1023
    const int col = g * 16 + (l & 15);
    const float4* src = (const float4*)w;           // [16384][64] float4
    float ss = 0.f;
    #pragma unroll
    for (int kk = 0; kk < 8; ++kk) {
        float4 v0 = src[(size_t)col * 64 + kk * 8 + (l >> 4) * 2];
        float4 v1 = src[(size_t)col * 64 + kk * 8 + (l >> 4) * 2 + 1];
        ss += v0.x * v0.x + v0.y * v0.y + v0.z * v0.z + v0.w * v0.w
            + v1.x * v1.x + v1.y * v1.y + v1.z * v1.z + v1.w * v1.w;
        uint4 o;
        o.x = bf16pack(v0.x, v0.y);
        o.y = bf16pack(v0.z, v0.w);
        o.z = bf16pack(v1.x, v1.y);
        o.w = bf16pack(v1.z, v1.w);
        Bfr[(size_t)g * 512 + kk * 64 + l] = o;     // uint4 units (16 B)
    }
    ss += __shfl_xor(ss, 16);
    ss += __shfl_xor(ss, 32);
    if (l < 16) b2[g * 16 + l] = ss;
}

// ---------------------------------------------------------------------------
// Main: LDS-free, barrier-free, 4-WAVES/SIMD MFMA distance GEMM.
// 1024 blocks (4/CU) x 256 thr; wave tile 32 rows x 16 cols -> afr[2][8] =
// 64 regs, total footprint ~120 <= 128 -> 4 waves/SIMD (the rounds-3..11
// invariant was 2/SIMD; TLP, not ILP, is the missing resource).
// B streams coalesced global->VGPR in quarter-buffered pairs (2 frags live,
// 2 in flight). 4 waves/block share a strip (L1 reuse); 4 strips/XCD.
// min-dist == max-(dot - b2/2); per-lane top-2, 5-bit chunk id in mantissa.
// ---------------------------------------------------------------------------
__global__ __launch_bounds__(256, 4) void som_mfma_kernel(
        const unsigned short* __restrict__ Abf, const unsigned short* __restrict__ Bfr,
        const float* __restrict__ b2, float* __restrict__ part) {
    const int t = threadIdx.x, l = t & 63;
    const int wid = t >> 6;
    const int x = blockIdx.x & 7, y = blockIdx.x >> 3;   // y: 0..127
    const int strip = x * 4 + (y & 3);                   // 4 strips per XCD
    const int m0 = (y >> 2) * 128 + wid * 32;            // 32 rows per wave

    // ---- A panel -> 64 regs (frag layout), pinned ----
    const char* gA = (const char*)Abf + (size_t)(m0 + (l & 15)) * 512 + (l >> 4) * 16;
    bf16x8 afr[2][8];
    #pragma unroll
    for (int mf = 0; mf < 2; ++mf)
        #pragma unroll
        for (int kk = 0; kk < 8; ++kk)
            afr[mf][kk] = *(const bf16x8*)(gA + mf * 8192 + kk * 64);
    #pragma unroll
    for (int mf = 0; mf < 2; ++mf)
        #pragma unroll
        for (int kk = 0; kk < 8; ++kk)
            asm volatile("" : "+v"(afr[mf][kk]));

    const char* gB = (const char*)Bfr + (size_t)strip * (STRIPW * 512) + l * 16;
    const float* b2s = b2 + strip * STRIPW + (l & 15);

    float r0[2][4], r1[2][4];
    #pragma unroll
    for (int mf = 0; mf < 2; ++mf)
        #pragma unroll
        for (int j = 0; j < 4; ++j) { r0[mf][j] = -FLT_MAX; r1[mf][j] = -FLT_MAX; }

    // prologue: frags 0,1 of chunk 0 + its b2
    bf16x8 p0 = *(const bf16x8*)(gB);
    bf16x8 p1 = *(const bf16x8*)(gB + 1024);
    float b2c = b2s[0];

    for (int c = 0; c < NCH; ++c) {
        const char* base = gB + (size_t)c * 8192;
        const float bi = -0.5f * b2c;
        f32x4 acc0 = (f32x4){bi, bi, bi, bi};
        f32x4 acc1 = acc0;

        bf16x8 n0 = *(const bf16x8*)(base + 2048);
        bf16x8 n1 = *(const bf16x8*)(base + 3072);
        acc0 = __builtin_amdgcn_mfma_f32_16x16x32_bf16(afr[0][0], p0, acc0, 0, 0, 0);
        acc1 = __builtin_amdgcn_mfma_f32_16x16x32_bf16(afr[1][0], p0, acc1, 0, 0, 0);
        acc0 = __builtin_amdgcn_mfma_f32_16x16x32_bf16(afr[0][1], p1, acc0, 0, 0, 0);
        acc1 = __builtin_amdgcn_mfma_f32_16x16x32_bf16(afr[1][1], p1, acc1, 0, 0, 0);

        p0 = *(const bf16x8*)(base + 4096);
        p1 = *(const bf16x8*)(base + 5120);
        acc0 = __builtin_amdgcn_mfma_f32_16x16x32_bf16(afr[0][2], n0, acc0, 0, 0, 0);
        acc1 = __builtin_amdgcn_mfma_f32_16x16x32_bf16(afr[1][2], n0, acc1, 0, 0, 0);
        acc0 = __builtin_amdgcn_mfma_f32_16x16x32_bf16(afr[0][3], n1, acc0, 0, 0, 0);
        acc1 = __builtin_amdgcn_mfma_f32_16x16x32_bf16(afr[1][3], n1, acc1, 0, 0, 0);

        n0 = *(const bf16x8*)(base + 6144);
        n1 = *(const bf16x8*)(base + 7168);
        acc0 = __builtin_amdgcn_mfma_f32_16x16x32_bf16(afr[0][4], p0, acc0, 0, 0, 0);
        acc1 = __builtin_amdgcn_mfma_f32_16x16x32_bf16(afr[1][4], p0, acc1, 0, 0, 0);
        acc0 = __builtin_amdgcn_mfma_f32_16x16x32_bf16(afr[0][5], p1, acc0, 0, 0, 0);
        acc1 = __builtin_amdgcn_mfma_f32_16x16x32_bf16(afr[1][5], p1, acc1, 0, 0, 0);

        float nb2 = b2c;
        if (c + 1 < NCH) {
            p0 = *(const bf16x8*)(base + 8192);
            p1 = *(const bf16x8*)(base + 9216);
            nb2 = b2s[(c + 1) * 16];
        }
        acc0 = __builtin_amdgcn_mfma_f32_16x16x32_bf16(afr[0][6], n0, acc0, 0, 0, 0);
        acc1 = __builtin_amdgcn_mfma_f32_16x16x32_bf16(afr[1][6], n0, acc1, 0, 0, 0);
        acc0 = __builtin_amdgcn_mfma_f32_16x16x32_bf16(afr[0][7], n1, acc0, 0, 0, 0);
        acc1 = __builtin_amdgcn_mfma_f32_16x16x32_bf16(afr[1][7], n1, acc1, 0, 0, 0);

        // top-2 fold: 5-bit chunk id in low mantissa bits (3 VALU/elem)
        const unsigned idn = (unsigned)c;
        #pragma unroll
        for (int j = 0; j < 4; ++j) {
            float pa = __uint_as_float((__float_as_uint(acc0[j]) & 0xFFFFFFE0u) | idn);
            float na = __builtin_amdgcn_fmed3f(r0[0][j], r1[0][j], pa);
            r0[0][j] = fmaxf(r0[0][j], pa);
            r1[0][j] = na;
            float pb = __uint_as_float((__float_as_uint(acc1[j]) & 0xFFFFFFE0u) | idn);
            float nb = __builtin_amdgcn_fmed3f(r0[1][j], r1[1][j], pb);
            r0[1][j] = fmaxf(r0[1][j], pb);
            r1[1][j] = nb;
        }
        b2c = nb2;
    }

    // ---- per-row merge over 16 lane-cols (repack 9-bit id); write part ----
    #pragma unroll
    for (int mf = 0; mf < 2; ++mf)
        #pragma unroll
        for (int j = 0; j < 4; ++j) {
            unsigned u0 = __float_as_uint(r0[mf][j]);
            unsigned u1 = __float_as_uint(r1[mf][j]);
            u0 = (u0 & 0xFFFFFC00u) | ((u0 & 31u) << 4) | (unsigned)(l & 15);
            u1 = (u1 & 0xFFFFFC00u) | ((u1 & 31u) << 4) | (unsigned)(l & 15);
            float v0 = __uint_as_float(u0), v1 = __uint_as_float(u1);
            #pragma unroll
            for (int off = 1; off < 16; off <<= 1) {
                float o0 = __shfl_xor(v0, off), o1 = __shfl_xor(v1, off);
                float nv1 = fmaxf(fminf(v0, o0), fmaxf(v1, o1));
                v0 = fmaxf(v0, o0);
                v1 = nv1;
            }
            if ((l & 15) == 0) {
                int row = m0 + mf * 16 + (l >> 4) * 4 + j;
                ((float2*)part)[(size_t)row * NSTRIP + strip] = make_float2(v0, v1);
            }
        }
}

// ---------------------------------------------------------------------------
// Refine: 1 wave per row over 64 packed entries (32 strips x top-2); exact
// fp32+sqrt recompute of candidates within margin; (dist, idx) argmin.
// ---------------------------------------------------------------------------
__global__ __launch_bounds__(256) void refine_kernel(
        const float* __restrict__ xb, const float* __restrict__ w,
        const float* __restrict__ a2, const float* __restrict__ b2,
        const float* __restrict__ part, int* __restrict__ out) {
    const int t = threadIdx.x, l = t & 63;
    const int row = blockIdx.x * 4 + (t >> 6);

    const float v = part[(size_t)row * (NSTRIP * 2) + l];
    float mx = v;
    #pragma unroll
    for (int off = 1; off < 64; off <<= 1) mx = fmaxf(mx, __shfl_xor(mx, off));
    const float cut = mx - UMARGIN;

    unsigned long long key = ~0ull;
    if (v >= cut) {
        unsigned b = __float_as_uint(v);
        int lane4 = b & 15, ch = (b >> 4) & 31, strip = l >> 1;
        int col = strip * STRIPW + ch * 16 + lane4;
        const float4* xr = (const float4*)(xb + (size_t)row * NFEAT);
        const float4* wr = (const float4*)(w + (size_t)col * NFEAT);
        float s0 = 0.f, s1 = 0.f, s2 = 0.f, s3 = 0.f;
        #pragma unroll
        for (int k = 0; k < 16; ++k) {
            float4 x0 = xr[4 * k + 0], w0 = wr[4 * k + 0];
            float4 x1 = xr[4 * k + 1], w1 = wr[4 * k + 1];
            float4 x2 = xr[4 * k + 2], w2 = wr[4 * k + 2];
            float4 x3 = xr[4 * k + 3], w3 = wr[4 * k + 3];
            s0 += x0.x * w0.x + x0.y * w0.y + x0.z * w0.z + x0.w * w0.w;
            s1 += x1.x * w1.x + x1.y * w1.y + x1.z * w1.z + x1.w * w1.w;
            s2 += x2.x * w2.x + x2.y * w2.y + x2.z * w2.z + x2.w * w2.w;
            s3 += x3.x * w3.x + x3.y * w3.y + x3.z * w3.z + x3.w * w3.w;
        }
        float dot = (s0 + s1) + (s2 + s3);
        float dd = a2[row] + b2[col] - 2.f * dot;
        float s = sqrtf(fmaxf(dd, 0.f));
        key = ((unsigned long long)__float_as_uint(s) << 32) | (unsigned)col;
    }
    #pragma unroll
    for (int off = 1; off < 64; off <<= 1) {
        unsigned long long o = __shfl_xor(key, off);
        key = o < key ? o : key;
    }
    if (l == 0) {
        int idx = (int)(key & 0xffffffffu);
        out[2 * row]     = idx >> 7;
        out[2 * row + 1] = idx & 127;
    }
}

extern "C" void kernel_launch(void* const* d_in, const int* in_sizes, int n_in,
                              void* d_out, int out_size, void* d_ws, size_t ws_size,
                              hipStream_t stream) {
    const float* xb = (const float*)d_in[0];   // (4096, 256)
    const float* w  = (const float*)d_in[1];   // (16384, 256)
    int* out = (int*)d_out;

    char* ws = (char*)d_ws;
    unsigned short* Abf = (unsigned short*)ws;                 // 2 MB
    unsigned short* Bfr = (unsigned short*)(ws + (2u << 20));  // 8 MB (frag order)
    float* a2   = (float*)(ws + (10u << 20));                  // 16 KB
    float* b2   = (float*)(ws + (10u << 20) + (64u << 10));    // 64 KB
    float* part = (float*)(ws + (10u << 20) + (128u << 10));   // 1 MB

    prep_a_kernel<<<(BATCH * 64) / 256, 256, 0, stream>>>(xb, (uint2*)Abf, a2);
    prep_b_kernel<<<MTOT / 64, 256, 0, stream>>>(w, (uint4*)Bfr, b2);
    som_mfma_kernel<<<1024, 256, 0, stream>>>(Abf, Bfr, b2, part);
    refine_kernel<<<BATCH / 4, 256, 0, stream>>>(xb, w, a2, b2, part, out);
}